// Round 7
// baseline (489.378 us; speedup 1.0000x reference)
//
#include <hip/hip_runtime.h>

#define H 64

typedef __attribute__((ext_vector_type(8))) short short8;
typedef __attribute__((ext_vector_type(4))) float floatx4;

__device__ __forceinline__ short bf16r(float f) {
    union { float f; unsigned u; } v; v.f = f;
    unsigned r = v.u + 0x7FFFu + ((v.u >> 16) & 1u);
    return (short)(r >> 16);
}

// ---------------- fused prep: weight B-frag packing + x->bf16 ----------------
__device__ __forceinline__ void pack_one(const float* W, short* out, int K, int KT, int tid)
{
    const int lane = tid & 63;
    const int nt = (tid >> 6) & 3;
    const int lk = tid >> 8;          // lay*KT + kt
    const int kt = lk % KT;
    const int lay = lk / KT;
    const int n = nt * 16 + (lane & 15);
    const int kbase = kt * 32 + ((lane >> 4) & 3) * 8;
    short8 v;
#pragma unroll
    for (int j = 0; j < 8; ++j) {
        const int k = kbase + j;
        const float w = (k < K) ? W[((size_t)lay * K + k) * H + n] : 0.f;
        v[j] = bf16r(w);
    }
    *(short8*)(out + (size_t)tid * 8) = v;
}

#define T_MW1 3840
#define T_MW2 1536
#define T_UW1 3072
#define T_UW2 1536

__global__ void prep_all(const float* __restrict__ mW1, const float* __restrict__ mW2,
                         const float* __restrict__ uW1, const float* __restrict__ uW2,
                         const float* __restrict__ x,
                         short* __restrict__ mW1f, short* __restrict__ mW2f,
                         short* __restrict__ uW1f, short* __restrict__ uW2f,
                         short* __restrict__ x16, int n8)
{
    int g = blockIdx.x * blockDim.x + threadIdx.x;
    if (g < T_MW1) { pack_one(mW1, mW1f, 144, 5, g); return; }
    g -= T_MW1;
    if (g < T_MW2) { pack_one(mW2, mW2f, 64, 2, g); return; }
    g -= T_MW2;
    if (g < T_UW1) { pack_one(uW1, uW1f, 128, 4, g); return; }
    g -= T_UW1;
    if (g < T_UW2) { pack_one(uW2, uW2f, 64, 2, g); return; }
    g -= T_UW2;
    if (g < n8) {
        const float4 a = ((const float4*)x)[2 * g];
        const float4 b = ((const float4*)x)[2 * g + 1];
        short8 v;
        v[0] = bf16r(a.x); v[1] = bf16r(a.y); v[2] = bf16r(a.z); v[3] = bf16r(a.w);
        v[4] = bf16r(b.x); v[5] = bf16r(b.y); v[6] = bf16r(b.z); v[7] = bf16r(b.w);
        ((short8*)x16)[g] = v;
    }
}

// ---------------- dst-sort prep ----------------
__global__ void hist_kernel(const int* __restrict__ edst, int* __restrict__ cnt, int E)
{
    int e = blockIdx.x * blockDim.x + threadIdx.x;
    if (e < E) atomicAdd(&cnt[edst[e]], 1);
}

__global__ void scan_block(const int* __restrict__ cnt, int* __restrict__ offs,
                           int* __restrict__ bsum, int n)
{
    __shared__ int buf[1024];
    const int t = threadIdx.x;
    const int gid = blockIdx.x * 1024 + t;
    const int v = (gid < n) ? cnt[gid] : 0;
    buf[t] = v;
    __syncthreads();
#pragma unroll
    for (int off = 1; off < 1024; off <<= 1) {
        int x = (t >= off) ? buf[t - off] : 0;
        __syncthreads();
        buf[t] += x;
        __syncthreads();
    }
    if (gid < n) offs[gid] = buf[t] - v;
    if (t == 1023) bsum[blockIdx.x] = buf[1023];
}

__global__ void scan_bsum(int* __restrict__ bsum, int nb)
{
    if (threadIdx.x == 0) {
        int acc = 0;
        for (int i = 0; i < nb; ++i) { int v = bsum[i]; bsum[i] = acc; acc += v; }
    }
}

__global__ void add_bsum(int* __restrict__ offs, const int* __restrict__ bsum, int n)
{
    int gid = blockIdx.x * blockDim.x + threadIdx.x;
    if (gid < n) offs[gid] += bsum[gid >> 10];
}

// scatter only small ints (src, dst, eperm) into sorted positions
__global__ void build_perm(const int* __restrict__ esrc, const int* __restrict__ edst,
                           int* __restrict__ offs,
                           int* __restrict__ src_s, int* __restrict__ dst_s,
                           int* __restrict__ eperm, int E)
{
    int e = blockIdx.x * blockDim.x + threadIdx.x;
    if (e >= E) return;
    const int d = edst[e];
    const int p = atomicAdd(&offs[d], 1);
    src_s[p] = esrc[e];
    dst_s[p] = d;
    eperm[p] = e;
}

// sequential-write ea16 gather: random full-line (64B) ea reads, coalesced writes
__global__ void gather_ea(const int* __restrict__ eperm, const float* __restrict__ ea,
                          short* __restrict__ ea16, int E)
{
    int i = blockIdx.x * blockDim.x + threadIdx.x;
    if (i >= E) return;
    const int e = eperm[i];
    const float4* r = (const float4*)(ea + (size_t)e * 16);
    const float4 a = r[0], b = r[1], c = r[2], d4 = r[3];
    short8 v0, v1;
    v0[0] = bf16r(a.x); v0[1] = bf16r(a.y); v0[2] = bf16r(a.z); v0[3] = bf16r(a.w);
    v0[4] = bf16r(b.x); v0[5] = bf16r(b.y); v0[6] = bf16r(b.z); v0[7] = bf16r(b.w);
    v1[0] = bf16r(c.x); v1[1] = bf16r(c.y); v1[2] = bf16r(c.z); v1[3] = bf16r(c.w);
    v1[4] = bf16r(d4.x); v1[5] = bf16r(d4.y); v1[6] = bf16r(d4.z); v1[7] = bf16r(d4.w);
    short8* o = (short8*)(ea16 + (size_t)i * 16);
    o[0] = v0; o[1] = v1;
}

// ---------------- edge-message MLP: zero-LDS A-path, 8 waves/EU ----------------
// 256 thr = 4 waves, 16 edges/wave. Wave-private LDS 4224 B (C1 bf16 then C2 fp32).
// Scatter: two 8-row register run-merges (VGPR diet for 8/EU occupancy).
__global__ __launch_bounds__(256, 8)
void edge_msg_mfma(const short* __restrict__ h16,
                   const int* __restrict__ src_s,
                   const int* __restrict__ dst_s,
                   const short* __restrict__ ea16,
                   const short* __restrict__ W1f, const float* __restrict__ b1,
                   const short* __restrict__ W2f, const float* __restrict__ b2,
                   float* __restrict__ agg)
{
    __shared__ char smraw[16896];
    const int t = threadIdx.x;
    const int w = t >> 6, l = t & 63, q = l >> 4, m15 = l & 15;
    const int i = blockIdx.x * 64 + w * 16 + m15;
    const int d = dst_s[i];
    const int s = src_s[i];

    short* C1 = (short*)(smraw + w * 4224);
    float* C2 = (float*)(smraw + w * 4224);

    const short8 a0 = *(const short8*)(h16 + (size_t)d * H + q * 8);
    const short8 a1 = *(const short8*)(h16 + (size_t)d * H + 32 + q * 8);
    const short8 a2 = *(const short8*)(h16 + (size_t)s * H + q * 8);
    const short8 a3 = *(const short8*)(h16 + (size_t)s * H + 32 + q * 8);
    short8 a4 = {0, 0, 0, 0, 0, 0, 0, 0};
    if (q < 2) a4 = *(const short8*)(ea16 + (size_t)i * 16 + q * 8);

    floatx4 acc[4] = {{0,0,0,0},{0,0,0,0},{0,0,0,0},{0,0,0,0}};
#pragma unroll
    for (int nt = 0; nt < 4; ++nt) {
        acc[nt] = __builtin_amdgcn_mfma_f32_16x16x32_bf16(a0, *(const short8*)(W1f + ((0*4+nt)*64 + l)*8), acc[nt], 0,0,0);
        acc[nt] = __builtin_amdgcn_mfma_f32_16x16x32_bf16(a1, *(const short8*)(W1f + ((1*4+nt)*64 + l)*8), acc[nt], 0,0,0);
        acc[nt] = __builtin_amdgcn_mfma_f32_16x16x32_bf16(a2, *(const short8*)(W1f + ((2*4+nt)*64 + l)*8), acc[nt], 0,0,0);
        acc[nt] = __builtin_amdgcn_mfma_f32_16x16x32_bf16(a3, *(const short8*)(W1f + ((3*4+nt)*64 + l)*8), acc[nt], 0,0,0);
        acc[nt] = __builtin_amdgcn_mfma_f32_16x16x32_bf16(a4, *(const short8*)(W1f + ((4*4+nt)*64 + l)*8), acc[nt], 0,0,0);
    }

#pragma unroll
    for (int nt = 0; nt < 4; ++nt) {
        const float bb = b1[nt * 16 + m15];
#pragma unroll
        for (int r = 0; r < 4; ++r)
            C1[(q * 4 + r) * 72 + nt * 16 + m15] = bf16r(fmaxf(acc[nt][r] + bb, 0.f));
    }

    const short8 p0 = *(const short8*)(C1 + m15 * 72 + q * 8);
    const short8 p1 = *(const short8*)(C1 + m15 * 72 + 32 + q * 8);

    floatx4 c2[4] = {{0,0,0,0},{0,0,0,0},{0,0,0,0},{0,0,0,0}};
#pragma unroll
    for (int nt = 0; nt < 4; ++nt) {
        c2[nt] = __builtin_amdgcn_mfma_f32_16x16x32_bf16(p0, *(const short8*)(W2f + ((0*4+nt)*64 + l)*8), c2[nt], 0,0,0);
        c2[nt] = __builtin_amdgcn_mfma_f32_16x16x32_bf16(p1, *(const short8*)(W2f + ((1*4+nt)*64 + l)*8), c2[nt], 0,0,0);
    }

#pragma unroll
    for (int nt = 0; nt < 4; ++nt) {
        const float bb = b2[nt * 16 + m15];
#pragma unroll
        for (int r = 0; r < 4; ++r)
            C2[(q * 4 + r) * 66 + nt * 16 + m15] = c2[nt][r] + bb;
    }

    // dst ids to SGPRs (lane mm of this wave holds row mm's dst)
    int dm[16];
#pragma unroll
    for (int mm = 0; mm < 16; ++mm)
        dm[mm] = __builtin_amdgcn_readlane(d, mm);

    // two 8-row run-merges (half-boundary split costs at most one extra atomic)
#pragma unroll
    for (int hf = 0; hf < 2; ++hf) {
        float v[8];
#pragma unroll
        for (int mm = 0; mm < 8; ++mm) v[mm] = C2[(hf * 8 + mm) * 66 + l];
        float run = v[0];
        int cur = dm[hf * 8];
#pragma unroll
        for (int mm = 1; mm < 8; ++mm) {
            if (dm[hf * 8 + mm] != cur) {
                atomicAdd(&agg[(size_t)cur * H + l], run);
                run = v[mm]; cur = dm[hf * 8 + mm];
            } else {
                run += v[mm];
            }
        }
        atomicAdd(&agg[(size_t)cur * H + l], run);
    }
}

// ---------------- node-update MLP: zero-LDS A-path, 8 waves/EU ----------------
__global__ __launch_bounds__(256, 8)
void node_update_mfma(const short* __restrict__ h16,
                      const float* __restrict__ agg,
                      const short* __restrict__ W1f, const float* __restrict__ b1,
                      const short* __restrict__ W2f, const float* __restrict__ b2,
                      short* __restrict__ h16out,        // non-final
                      const int* __restrict__ batch,     // final
                      float* __restrict__ pooled, float* __restrict__ counts,
                      int N)
{
    __shared__ char smraw[16896];
    const int t = threadIdx.x;
    const int w = t >> 6, l = t & 63, q = l >> 4, m15 = l & 15;
    const int n0 = blockIdx.x * 64;
    const int n = n0 + w * 16 + m15;
    const bool ok = n < N;

    short* C1 = (short*)(smraw + w * 4224);
    float* C2 = (float*)(smraw + w * 4224);

    short8 a0 = {0,0,0,0,0,0,0,0}, a1 = a0, a2 = a0, a3 = a0;
    if (ok) {
        a0 = *(const short8*)(h16 + (size_t)n * H + q * 8);
        a1 = *(const short8*)(h16 + (size_t)n * H + 32 + q * 8);
        const float4 f0 = *(const float4*)(agg + (size_t)n * H + q * 8);
        const float4 f1 = *(const float4*)(agg + (size_t)n * H + q * 8 + 4);
        const float4 f2 = *(const float4*)(agg + (size_t)n * H + 32 + q * 8);
        const float4 f3 = *(const float4*)(agg + (size_t)n * H + 32 + q * 8 + 4);
        a2[0] = bf16r(f0.x); a2[1] = bf16r(f0.y); a2[2] = bf16r(f0.z); a2[3] = bf16r(f0.w);
        a2[4] = bf16r(f1.x); a2[5] = bf16r(f1.y); a2[6] = bf16r(f1.z); a2[7] = bf16r(f1.w);
        a3[0] = bf16r(f2.x); a3[1] = bf16r(f2.y); a3[2] = bf16r(f2.z); a3[3] = bf16r(f2.w);
        a3[4] = bf16r(f3.x); a3[5] = bf16r(f3.y); a3[6] = bf16r(f3.z); a3[7] = bf16r(f3.w);
    }

    floatx4 acc[4] = {{0,0,0,0},{0,0,0,0},{0,0,0,0},{0,0,0,0}};
#pragma unroll
    for (int nt = 0; nt < 4; ++nt) {
        acc[nt] = __builtin_amdgcn_mfma_f32_16x16x32_bf16(a0, *(const short8*)(W1f + ((0*4+nt)*64 + l)*8), acc[nt], 0,0,0);
        acc[nt] = __builtin_amdgcn_mfma_f32_16x16x32_bf16(a1, *(const short8*)(W1f + ((1*4+nt)*64 + l)*8), acc[nt], 0,0,0);
        acc[nt] = __builtin_amdgcn_mfma_f32_16x16x32_bf16(a2, *(const short8*)(W1f + ((2*4+nt)*64 + l)*8), acc[nt], 0,0,0);
        acc[nt] = __builtin_amdgcn_mfma_f32_16x16x32_bf16(a3, *(const short8*)(W1f + ((3*4+nt)*64 + l)*8), acc[nt], 0,0,0);
    }

#pragma unroll
    for (int nt = 0; nt < 4; ++nt) {
        const float bb = b1[nt * 16 + m15];
#pragma unroll
        for (int r = 0; r < 4; ++r)
            C1[(q * 4 + r) * 72 + nt * 16 + m15] = bf16r(fmaxf(acc[nt][r] + bb, 0.f));
    }

    const short8 p0 = *(const short8*)(C1 + m15 * 72 + q * 8);
    const short8 p1 = *(const short8*)(C1 + m15 * 72 + 32 + q * 8);

    floatx4 c2[4] = {{0,0,0,0},{0,0,0,0},{0,0,0,0},{0,0,0,0}};
#pragma unroll
    for (int nt = 0; nt < 4; ++nt) {
        c2[nt] = __builtin_amdgcn_mfma_f32_16x16x32_bf16(p0, *(const short8*)(W2f + ((0*4+nt)*64 + l)*8), c2[nt], 0,0,0);
        c2[nt] = __builtin_amdgcn_mfma_f32_16x16x32_bf16(p1, *(const short8*)(W2f + ((1*4+nt)*64 + l)*8), c2[nt], 0,0,0);
    }

    if (!batch) {
#pragma unroll
        for (int nt = 0; nt < 4; ++nt) {
            const float bb = b2[nt * 16 + m15];
#pragma unroll
            for (int r = 0; r < 4; ++r) {
                const int nn = n0 + w * 16 + q * 4 + r;
                if (nn < N)
                    h16out[(size_t)nn * H + nt * 16 + m15] =
                        bf16r(fmaxf(c2[nt][r] + bb, 0.f));
            }
        }
        return;
    }

    // final layer: outer relu -> C2 -> two-half register run-merge mean-pool
#pragma unroll
    for (int nt = 0; nt < 4; ++nt) {
        const float bb = b2[nt * 16 + m15];
#pragma unroll
        for (int r = 0; r < 4; ++r)
            C2[(q * 4 + r) * 66 + nt * 16 + m15] = fmaxf(c2[nt][r] + bb, 0.f);
    }

    const int bi = ok ? batch[n] : -1;
    int bm[16];
#pragma unroll
    for (int mm = 0; mm < 16; ++mm)
        bm[mm] = __builtin_amdgcn_readlane(bi, mm);

#pragma unroll
    for (int hf = 0; hf < 2; ++hf) {
        float v[8];
#pragma unroll
        for (int mm = 0; mm < 8; ++mm) v[mm] = C2[(hf * 8 + mm) * 66 + l];
        float run = v[0];
        int cur = bm[hf * 8];
        int len = 1;
#pragma unroll
        for (int mm = 1; mm < 8; ++mm) {
            if (bm[hf * 8 + mm] != cur) {
                if (cur >= 0) {
                    atomicAdd(&pooled[(size_t)cur * H + l], run);
                    if (l == 0) atomicAdd(&counts[cur], (float)len);
                }
                run = v[mm]; cur = bm[hf * 8 + mm]; len = 1;
            } else {
                run += v[mm]; ++len;
            }
        }
        if (cur >= 0) {
            atomicAdd(&pooled[(size_t)cur * H + l], run);
            if (l == 0) atomicAdd(&counts[cur], (float)len);
        }
    }
}

// ---------------- head ----------------
__global__ void head_kernel(const float* __restrict__ pooled,
                            const float* __restrict__ counts,
                            const float* __restrict__ lin1w,
                            const float* __restrict__ lin1b,
                            const float* __restrict__ lin2w,
                            const float* __restrict__ lin2b,
                            float* __restrict__ out, int G)
{
    int g = blockIdx.x;
    int j = threadIdx.x;
    __shared__ float p[H];
    float c = fmaxf(counts[g], 1.0f);
    p[j] = pooled[(size_t)g * H + j] / c;
    __syncthreads();

    float accj = lin1b[j];
#pragma unroll
    for (int k = 0; k < H; ++k) accj = fmaf(p[k], lin1w[k * H + j], accj);
    accj = fmaxf(accj, 0.0f) * lin2w[j];
#pragma unroll
    for (int off = 32; off >= 1; off >>= 1) accj += __shfl_down(accj, off);
    if (j == 0) out[g] = accj + lin2b[0];
}

extern "C" void kernel_launch(void* const* d_in, const int* in_sizes, int n_in,
                              void* d_out, int out_size, void* d_ws, size_t ws_size,
                              hipStream_t stream)
{
    const float* x      = (const float*)d_in[0];
    const int*   eidx   = (const int*)d_in[1];
    const float* ea     = (const float*)d_in[2];
    const int*   batch  = (const int*)d_in[3];
    const float* mW1    = (const float*)d_in[4];
    const float* mb1    = (const float*)d_in[5];
    const float* mW2    = (const float*)d_in[6];
    const float* mb2    = (const float*)d_in[7];
    const float* uW1    = (const float*)d_in[8];
    const float* ub1    = (const float*)d_in[9];
    const float* uW2    = (const float*)d_in[10];
    const float* ub2    = (const float*)d_in[11];
    const float* lin1w  = (const float*)d_in[12];
    const float* lin1b  = (const float*)d_in[13];
    const float* lin2w  = (const float*)d_in[14];
    const float* lin2b  = (const float*)d_in[15];

    const int N = in_sizes[0] / H;
    const int E = in_sizes[1] / 2;
    const int G = out_size;

    // ---- workspace ----
    short* mW1f = (short*)d_ws;
    short* mW2f = mW1f + 30720;
    short* uW1f = mW2f + 12288;
    short* uW2f = uW1f + 24576;
    short* x16  = uW2f + 12288;
    short* h16A = x16  + (size_t)N * H;
    short* h16B = h16A + (size_t)N * H;
    short* ea16 = h16B + (size_t)N * H;
    char*  pch  = (char*)(ea16 + (size_t)E * 16);
    int* offs   = (int*)pch;          pch += (size_t)N * 4;
    int* bsum   = (int*)pch;          pch += 256;
    int* src_s  = (int*)pch;          pch += (size_t)E * 4;
    int* dst_s  = (int*)pch;          pch += (size_t)E * 4;
    int* eperm  = (int*)pch;          pch += (size_t)E * 4;
    int*   cnt    = (int*)pch;
    float* agg3   = (float*)(pch + (size_t)N * 4);
    float* pooled = agg3 + (size_t)3 * N * H;
    float* counts = pooled + (size_t)G * H;
    const size_t zero_bytes = (size_t)N * 4 + ((size_t)3 * N * H + (size_t)G * H + G) * 4;

    const int* esrc = eidx;
    const int* edst = eidx + E;

    {
        const int n8 = N * H / 8;
        const int total = T_MW1 + T_MW2 + T_UW1 + T_UW2 + n8;
        prep_all<<<(total + 255) / 256, 256, 0, stream>>>(
            mW1, mW2, uW1, uW2, x, mW1f, mW2f, uW1f, uW2f, x16, n8);
    }

    hipMemsetAsync(cnt, 0, zero_bytes, stream);

    hist_kernel<<<(E + 255) / 256, 256, 0, stream>>>(edst, cnt, E);
    {
        const int nb = (N + 1023) / 1024;
        scan_block<<<nb, 1024, 0, stream>>>(cnt, offs, bsum, N);
        scan_bsum<<<1, 64, 0, stream>>>(bsum, nb);
        add_bsum<<<(N + 255) / 256, 256, 0, stream>>>(offs, bsum, N);
    }
    build_perm<<<(E + 255) / 256, 256, 0, stream>>>(esrc, edst, offs, src_s, dst_s, eperm, E);
    gather_ea<<<(E + 255) / 256, 256, 0, stream>>>(eperm, ea, ea16, E);

    const short* hin = x16;
    short* houts16[3] = {h16A, h16B, nullptr};
    const int nEB = E / 64;
    const int nNB = (N + 63) / 64;

    for (int lyr = 0; lyr < 3; ++lyr) {
        float* agg = agg3 + (size_t)lyr * N * H;
        edge_msg_mfma<<<nEB, 256, 0, stream>>>(
            hin, src_s, dst_s, ea16,
            mW1f + (size_t)lyr * 10240, mb1 + (size_t)lyr * H,
            mW2f + (size_t)lyr * 4096,  mb2 + (size_t)lyr * H,
            agg);
        node_update_mfma<<<nNB, 256, 0, stream>>>(
            hin, agg,
            uW1f + (size_t)lyr * 8192, ub1 + (size_t)lyr * H,
            uW2f + (size_t)lyr * 4096, ub2 + (size_t)lyr * H,
            houts16[lyr],
            (lyr == 2) ? batch : (const int*)nullptr,
            pooled, counts, N);
        hin = houts16[lyr];
    }

    head_kernel<<<G, H, 0, stream>>>(pooled, counts, lin1w, lin1b, lin2w, lin2b,
                                     (float*)d_out, G);
}

// Round 8
// 472.444 us; speedup vs baseline: 1.0358x; 1.0358x over previous
//
#include <hip/hip_runtime.h>

#define H 64

typedef __attribute__((ext_vector_type(8))) short short8;
typedef __attribute__((ext_vector_type(4))) float floatx4;

__device__ __forceinline__ short bf16r(float f) {
    union { float f; unsigned u; } v; v.f = f;
    unsigned r = v.u + 0x7FFFu + ((v.u >> 16) & 1u);
    return (short)(r >> 16);
}

// ---------------- fused prep: weight B-frag packing + x->bf16 ----------------
__device__ __forceinline__ void pack_one(const float* W, short* out, int K, int KT, int tid)
{
    const int lane = tid & 63;
    const int nt = (tid >> 6) & 3;
    const int lk = tid >> 8;
    const int kt = lk % KT;
    const int lay = lk / KT;
    const int n = nt * 16 + (lane & 15);
    const int kbase = kt * 32 + ((lane >> 4) & 3) * 8;
    short8 v;
#pragma unroll
    for (int j = 0; j < 8; ++j) {
        const int k = kbase + j;
        const float w = (k < K) ? W[((size_t)lay * K + k) * H + n] : 0.f;
        v[j] = bf16r(w);
    }
    *(short8*)(out + (size_t)tid * 8) = v;
}

#define T_MW1 3840
#define T_MW2 1536
#define T_UW1 3072
#define T_UW2 1536

__global__ void prep_all(const float* __restrict__ mW1, const float* __restrict__ mW2,
                         const float* __restrict__ uW1, const float* __restrict__ uW2,
                         const float* __restrict__ x,
                         short* __restrict__ mW1f, short* __restrict__ mW2f,
                         short* __restrict__ uW1f, short* __restrict__ uW2f,
                         short* __restrict__ x16, int n8)
{
    int g = blockIdx.x * blockDim.x + threadIdx.x;
    if (g < T_MW1) { pack_one(mW1, mW1f, 144, 5, g); return; }
    g -= T_MW1;
    if (g < T_MW2) { pack_one(mW2, mW2f, 64, 2, g); return; }
    g -= T_MW2;
    if (g < T_UW1) { pack_one(uW1, uW1f, 128, 4, g); return; }
    g -= T_UW1;
    if (g < T_UW2) { pack_one(uW2, uW2f, 64, 2, g); return; }
    g -= T_UW2;
    if (g < n8) {
        const float4 a = ((const float4*)x)[2 * g];
        const float4 b = ((const float4*)x)[2 * g + 1];
        short8 v;
        v[0] = bf16r(a.x); v[1] = bf16r(a.y); v[2] = bf16r(a.z); v[3] = bf16r(a.w);
        v[4] = bf16r(b.x); v[5] = bf16r(b.y); v[6] = bf16r(b.z); v[7] = bf16r(b.w);
        ((short8*)x16)[g] = v;
    }
}

// ---------------- dst-sort prep ----------------
__global__ void hist_kernel(const int* __restrict__ edst, int* __restrict__ cnt, int E)
{
    int e = blockIdx.x * blockDim.x + threadIdx.x;
    if (e < E) atomicAdd(&cnt[edst[e]], 1);
}

__global__ void scan_block(const int* __restrict__ cnt, int* __restrict__ offs,
                           int* __restrict__ bsum, int n)
{
    __shared__ int buf[1024];
    const int t = threadIdx.x;
    const int gid = blockIdx.x * 1024 + t;
    const int v = (gid < n) ? cnt[gid] : 0;
    buf[t] = v;
    __syncthreads();
#pragma unroll
    for (int off = 1; off < 1024; off <<= 1) {
        int x = (t >= off) ? buf[t - off] : 0;
        __syncthreads();
        buf[t] += x;
        __syncthreads();
    }
    if (gid < n) offs[gid] = buf[t] - v;
    if (t == 1023) bsum[blockIdx.x] = buf[1023];
}

__global__ void scan_bsum(int* __restrict__ bsum, int nb)
{
    if (threadIdx.x == 0) {
        int acc = 0;
        for (int i = 0; i < nb; ++i) { int v = bsum[i]; bsum[i] = acc; acc += v; }
    }
}

__global__ void add_bsum(int* __restrict__ offs, const int* __restrict__ bsum, int n)
{
    int gid = blockIdx.x * blockDim.x + threadIdx.x;
    if (gid < n) offs[gid] += bsum[gid >> 10];
}

// combined: permutation + gather src/dst/edge_attr(bf16) into sorted order
__global__ void build_perm_gather(const int* __restrict__ esrc, const int* __restrict__ edst,
                                  const float* __restrict__ ea, int* __restrict__ offs,
                                  int* __restrict__ src_s, int* __restrict__ dst_s,
                                  short* __restrict__ ea16, int E)
{
    int e = blockIdx.x * blockDim.x + threadIdx.x;
    if (e >= E) return;
    const int d = edst[e];
    const int p = atomicAdd(&offs[d], 1);
    src_s[p] = esrc[e];
    dst_s[p] = d;
    const float4* r = (const float4*)(ea + (size_t)e * 16);
    const float4 a = r[0], b = r[1], c = r[2], d4 = r[3];
    short8 v0, v1;
    v0[0] = bf16r(a.x); v0[1] = bf16r(a.y); v0[2] = bf16r(a.z); v0[3] = bf16r(a.w);
    v0[4] = bf16r(b.x); v0[5] = bf16r(b.y); v0[6] = bf16r(b.z); v0[7] = bf16r(b.w);
    v1[0] = bf16r(c.x); v1[1] = bf16r(c.y); v1[2] = bf16r(c.z); v1[3] = bf16r(c.w);
    v1[4] = bf16r(d4.x); v1[5] = bf16r(d4.y); v1[6] = bf16r(d4.z); v1[7] = bf16r(d4.w);
    short8* o = (short8*)(ea16 + (size_t)p * 16);
    o[0] = v0; o[1] = v1;
}

// ---------------- edge-message MLP: resident weights, T=8 tiles/wave ----------------
// block = 256 thr = 4 waves; each wave processes 8 consecutive 16-edge tiles (128 edges).
// W1/W2 B-fragments loaded into VGPRs ONCE per wave (kills the dominant TA term).
// Run-merge scatter carries (cur,run) across tiles; one flush at wave end.
__global__ __launch_bounds__(256, 2)
void edge_msg_mfma(const short* __restrict__ h16,
                   const int* __restrict__ src_s,
                   const int* __restrict__ dst_s,
                   const short* __restrict__ ea16,
                   const short* __restrict__ W1f, const float* __restrict__ b1,
                   const short* __restrict__ W2f, const float* __restrict__ b2,
                   float* __restrict__ agg, int nTiles)
{
    __shared__ char smraw[16896];
    const int t = threadIdx.x;
    const int w = t >> 6, l = t & 63, q = l >> 4, m15 = l & 15;

    short* C1 = (short*)(smraw + w * 4224);
    float* C2 = (float*)(smraw + w * 4224);

    // ---- resident weights: 20 + 8 B-fragments (112 VGPR) ----
    short8 W1r[20], W2r[8];
#pragma unroll
    for (int k = 0; k < 20; ++k) W1r[k] = *(const short8*)(W1f + ((size_t)(k * 64 + l)) * 8);
#pragma unroll
    for (int k = 0; k < 8; ++k)  W2r[k] = *(const short8*)(W2f + ((size_t)(k * 64 + l)) * 8);
    float b1v[4], b2v[4];
#pragma unroll
    for (int nt = 0; nt < 4; ++nt) { b1v[nt] = b1[nt * 16 + m15]; b2v[nt] = b2[nt * 16 + m15]; }

    const int tb0 = (blockIdx.x * 4 + w) * 8;
    float run = 0.f;
    int cur = -1;

#pragma unroll 1
    for (int tt = 0; tt < 8; ++tt) {
        const int tb = tb0 + tt;
        if (tb >= nTiles) break;
        const int i = tb * 16 + m15;
        const int d = dst_s[i];
        const int s = src_s[i];

        const short8 a0 = *(const short8*)(h16 + (size_t)d * H + q * 8);
        const short8 a1 = *(const short8*)(h16 + (size_t)d * H + 32 + q * 8);
        const short8 a2 = *(const short8*)(h16 + (size_t)s * H + q * 8);
        const short8 a3 = *(const short8*)(h16 + (size_t)s * H + 32 + q * 8);
        short8 a4 = {0, 0, 0, 0, 0, 0, 0, 0};
        if (q < 2) a4 = *(const short8*)(ea16 + (size_t)i * 16 + q * 8);

        floatx4 acc[4] = {{0,0,0,0},{0,0,0,0},{0,0,0,0},{0,0,0,0}};
#pragma unroll
        for (int nt = 0; nt < 4; ++nt) {
            acc[nt] = __builtin_amdgcn_mfma_f32_16x16x32_bf16(a0, W1r[0*4+nt], acc[nt], 0,0,0);
            acc[nt] = __builtin_amdgcn_mfma_f32_16x16x32_bf16(a1, W1r[1*4+nt], acc[nt], 0,0,0);
            acc[nt] = __builtin_amdgcn_mfma_f32_16x16x32_bf16(a2, W1r[2*4+nt], acc[nt], 0,0,0);
            acc[nt] = __builtin_amdgcn_mfma_f32_16x16x32_bf16(a3, W1r[3*4+nt], acc[nt], 0,0,0);
            acc[nt] = __builtin_amdgcn_mfma_f32_16x16x32_bf16(a4, W1r[4*4+nt], acc[nt], 0,0,0);
        }

#pragma unroll
        for (int nt = 0; nt < 4; ++nt)
#pragma unroll
            for (int r = 0; r < 4; ++r)
                C1[(q * 4 + r) * 72 + nt * 16 + m15] = bf16r(fmaxf(acc[nt][r] + b1v[nt], 0.f));

        const short8 p0 = *(const short8*)(C1 + m15 * 72 + q * 8);
        const short8 p1 = *(const short8*)(C1 + m15 * 72 + 32 + q * 8);

        floatx4 c2[4] = {{0,0,0,0},{0,0,0,0},{0,0,0,0},{0,0,0,0}};
#pragma unroll
        for (int nt = 0; nt < 4; ++nt) {
            c2[nt] = __builtin_amdgcn_mfma_f32_16x16x32_bf16(p0, W2r[0*4+nt], c2[nt], 0,0,0);
            c2[nt] = __builtin_amdgcn_mfma_f32_16x16x32_bf16(p1, W2r[1*4+nt], c2[nt], 0,0,0);
        }

#pragma unroll
        for (int nt = 0; nt < 4; ++nt)
#pragma unroll
            for (int r = 0; r < 4; ++r)
                C2[(q * 4 + r) * 66 + nt * 16 + m15] = c2[nt][r] + b2v[nt];

        int dm[16];
#pragma unroll
        for (int mm = 0; mm < 16; ++mm)
            dm[mm] = __builtin_amdgcn_readlane(d, mm);

        // run-merge with carry across halves AND tiles
#pragma unroll
        for (int hf = 0; hf < 2; ++hf) {
            float vv[8];
#pragma unroll
            for (int mm = 0; mm < 8; ++mm) vv[mm] = C2[(hf * 8 + mm) * 66 + l];
#pragma unroll
            for (int mm = 0; mm < 8; ++mm) {
                const int dd = dm[hf * 8 + mm];
                if (dd != cur) {
                    if (cur >= 0) atomicAdd(&agg[(size_t)cur * H + l], run);
                    run = vv[mm]; cur = dd;
                } else {
                    run += vv[mm];
                }
            }
        }
    }
    if (cur >= 0) atomicAdd(&agg[(size_t)cur * H + l], run);
}

// ---------------- node-update MLP: resident weights, T=2 tiles/wave ----------------
__global__ __launch_bounds__(256, 2)
void node_update_mfma(const short* __restrict__ h16,
                      const float* __restrict__ agg,
                      const short* __restrict__ W1f, const float* __restrict__ b1,
                      const short* __restrict__ W2f, const float* __restrict__ b2,
                      short* __restrict__ h16out,        // non-final
                      const int* __restrict__ batch,     // final
                      float* __restrict__ pooled, float* __restrict__ counts,
                      int N, int nTiles)
{
    __shared__ char smraw[16896];
    const int t = threadIdx.x;
    const int w = t >> 6, l = t & 63, q = l >> 4, m15 = l & 15;

    short* C1 = (short*)(smraw + w * 4224);
    float* C2 = (float*)(smraw + w * 4224);

    short8 W1r[16], W2r[8];
#pragma unroll
    for (int k = 0; k < 16; ++k) W1r[k] = *(const short8*)(W1f + ((size_t)(k * 64 + l)) * 8);
#pragma unroll
    for (int k = 0; k < 8; ++k)  W2r[k] = *(const short8*)(W2f + ((size_t)(k * 64 + l)) * 8);
    float b1v[4], b2v[4];
#pragma unroll
    for (int nt = 0; nt < 4; ++nt) { b1v[nt] = b1[nt * 16 + m15]; b2v[nt] = b2[nt * 16 + m15]; }

    const int tb0 = (blockIdx.x * 4 + w) * 2;
    float run = 0.f;
    int cur = -1, len = 0;

#pragma unroll 1
    for (int tt = 0; tt < 2; ++tt) {
        const int tb = tb0 + tt;
        if (tb >= nTiles) break;
        const int n = tb * 16 + m15;
        const bool ok = n < N;

        short8 a0 = {0,0,0,0,0,0,0,0}, a1 = a0, a2 = a0, a3 = a0;
        if (ok) {
            a0 = *(const short8*)(h16 + (size_t)n * H + q * 8);
            a1 = *(const short8*)(h16 + (size_t)n * H + 32 + q * 8);
            const float4 f0 = *(const float4*)(agg + (size_t)n * H + q * 8);
            const float4 f1 = *(const float4*)(agg + (size_t)n * H + q * 8 + 4);
            const float4 f2 = *(const float4*)(agg + (size_t)n * H + 32 + q * 8);
            const float4 f3 = *(const float4*)(agg + (size_t)n * H + 32 + q * 8 + 4);
            a2[0] = bf16r(f0.x); a2[1] = bf16r(f0.y); a2[2] = bf16r(f0.z); a2[3] = bf16r(f0.w);
            a2[4] = bf16r(f1.x); a2[5] = bf16r(f1.y); a2[6] = bf16r(f1.z); a2[7] = bf16r(f1.w);
            a3[0] = bf16r(f2.x); a3[1] = bf16r(f2.y); a3[2] = bf16r(f2.z); a3[3] = bf16r(f2.w);
            a3[4] = bf16r(f3.x); a3[5] = bf16r(f3.y); a3[6] = bf16r(f3.z); a3[7] = bf16r(f3.w);
        }

        floatx4 acc[4] = {{0,0,0,0},{0,0,0,0},{0,0,0,0},{0,0,0,0}};
#pragma unroll
        for (int nt = 0; nt < 4; ++nt) {
            acc[nt] = __builtin_amdgcn_mfma_f32_16x16x32_bf16(a0, W1r[0*4+nt], acc[nt], 0,0,0);
            acc[nt] = __builtin_amdgcn_mfma_f32_16x16x32_bf16(a1, W1r[1*4+nt], acc[nt], 0,0,0);
            acc[nt] = __builtin_amdgcn_mfma_f32_16x16x32_bf16(a2, W1r[2*4+nt], acc[nt], 0,0,0);
            acc[nt] = __builtin_amdgcn_mfma_f32_16x16x32_bf16(a3, W1r[3*4+nt], acc[nt], 0,0,0);
        }

#pragma unroll
        for (int nt = 0; nt < 4; ++nt)
#pragma unroll
            for (int r = 0; r < 4; ++r)
                C1[(q * 4 + r) * 72 + nt * 16 + m15] = bf16r(fmaxf(acc[nt][r] + b1v[nt], 0.f));

        const short8 p0 = *(const short8*)(C1 + m15 * 72 + q * 8);
        const short8 p1 = *(const short8*)(C1 + m15 * 72 + 32 + q * 8);

        floatx4 c2[4] = {{0,0,0,0},{0,0,0,0},{0,0,0,0},{0,0,0,0}};
#pragma unroll
        for (int nt = 0; nt < 4; ++nt) {
            c2[nt] = __builtin_amdgcn_mfma_f32_16x16x32_bf16(p0, W2r[0*4+nt], c2[nt], 0,0,0);
            c2[nt] = __builtin_amdgcn_mfma_f32_16x16x32_bf16(p1, W2r[1*4+nt], c2[nt], 0,0,0);
        }

        if (!batch) {
#pragma unroll
            for (int nt = 0; nt < 4; ++nt)
#pragma unroll
                for (int r = 0; r < 4; ++r) {
                    const int nn = tb * 16 + q * 4 + r;
                    if (nn < N)
                        h16out[(size_t)nn * H + nt * 16 + m15] =
                            bf16r(fmaxf(c2[nt][r] + b2v[nt], 0.f));
                }
            continue;
        }

        // final layer: outer relu -> C2 -> run-merge mean-pool with cross-tile carry
#pragma unroll
        for (int nt = 0; nt < 4; ++nt)
#pragma unroll
            for (int r = 0; r < 4; ++r)
                C2[(q * 4 + r) * 66 + nt * 16 + m15] = fmaxf(c2[nt][r] + b2v[nt], 0.f);

        const int bi = ok ? batch[n] : -1;
        int bm[16];
#pragma unroll
        for (int mm = 0; mm < 16; ++mm)
            bm[mm] = __builtin_amdgcn_readlane(bi, mm);

#pragma unroll
        for (int hf = 0; hf < 2; ++hf) {
            float vv[8];
#pragma unroll
            for (int mm = 0; mm < 8; ++mm) vv[mm] = C2[(hf * 8 + mm) * 66 + l];
#pragma unroll
            for (int mm = 0; mm < 8; ++mm) {
                const int bb = bm[hf * 8 + mm];
                if (bb != cur) {
                    if (cur >= 0) {
                        atomicAdd(&pooled[(size_t)cur * H + l], run);
                        if (l == 0) atomicAdd(&counts[cur], (float)len);
                    }
                    run = vv[mm]; cur = bb; len = 1;
                } else {
                    run += vv[mm]; ++len;
                }
            }
        }
    }
    if (batch && cur >= 0) {
        atomicAdd(&pooled[(size_t)cur * H + l], run);
        if (l == 0) atomicAdd(&counts[cur], (float)len);
    }
}

// ---------------- head ----------------
__global__ void head_kernel(const float* __restrict__ pooled,
                            const float* __restrict__ counts,
                            const float* __restrict__ lin1w,
                            const float* __restrict__ lin1b,
                            const float* __restrict__ lin2w,
                            const float* __restrict__ lin2b,
                            float* __restrict__ out, int G)
{
    int g = blockIdx.x;
    int j = threadIdx.x;
    __shared__ float p[H];
    float c = fmaxf(counts[g], 1.0f);
    p[j] = pooled[(size_t)g * H + j] / c;
    __syncthreads();

    float accj = lin1b[j];
#pragma unroll
    for (int k = 0; k < H; ++k) accj = fmaf(p[k], lin1w[k * H + j], accj);
    accj = fmaxf(accj, 0.0f) * lin2w[j];
#pragma unroll
    for (int off = 32; off >= 1; off >>= 1) accj += __shfl_down(accj, off);
    if (j == 0) out[g] = accj + lin2b[0];
}

extern "C" void kernel_launch(void* const* d_in, const int* in_sizes, int n_in,
                              void* d_out, int out_size, void* d_ws, size_t ws_size,
                              hipStream_t stream)
{
    const float* x      = (const float*)d_in[0];
    const int*   eidx   = (const int*)d_in[1];
    const float* ea     = (const float*)d_in[2];
    const int*   batch  = (const int*)d_in[3];
    const float* mW1    = (const float*)d_in[4];
    const float* mb1    = (const float*)d_in[5];
    const float* mW2    = (const float*)d_in[6];
    const float* mb2    = (const float*)d_in[7];
    const float* uW1    = (const float*)d_in[8];
    const float* ub1    = (const float*)d_in[9];
    const float* uW2    = (const float*)d_in[10];
    const float* ub2    = (const float*)d_in[11];
    const float* lin1w  = (const float*)d_in[12];
    const float* lin1b  = (const float*)d_in[13];
    const float* lin2w  = (const float*)d_in[14];
    const float* lin2b  = (const float*)d_in[15];

    const int N = in_sizes[0] / H;
    const int E = in_sizes[1] / 2;
    const int G = out_size;

    // ---- workspace ----
    short* mW1f = (short*)d_ws;
    short* mW2f = mW1f + 30720;
    short* uW1f = mW2f + 12288;
    short* uW2f = uW1f + 24576;
    short* x16  = uW2f + 12288;
    short* h16A = x16  + (size_t)N * H;
    short* h16B = h16A + (size_t)N * H;
    short* ea16 = h16B + (size_t)N * H;
    char*  pch  = (char*)(ea16 + (size_t)E * 16);
    int* offs   = (int*)pch;          pch += (size_t)N * 4;
    int* bsum   = (int*)pch;          pch += 256;
    int* src_s  = (int*)pch;          pch += (size_t)E * 4;
    int* dst_s  = (int*)pch;          pch += (size_t)E * 4;
    int*   cnt    = (int*)pch;
    float* agg3   = (float*)(pch + (size_t)N * 4);
    float* pooled = agg3 + (size_t)3 * N * H;
    float* counts = pooled + (size_t)G * H;
    const size_t zero_bytes = (size_t)N * 4 + ((size_t)3 * N * H + (size_t)G * H + G) * 4;

    const int* esrc = eidx;
    const int* edst = eidx + E;

    {
        const int n8 = N * H / 8;
        const int total = T_MW1 + T_MW2 + T_UW1 + T_UW2 + n8;
        prep_all<<<(total + 255) / 256, 256, 0, stream>>>(
            mW1, mW2, uW1, uW2, x, mW1f, mW2f, uW1f, uW2f, x16, n8);
    }

    hipMemsetAsync(cnt, 0, zero_bytes, stream);

    hist_kernel<<<(E + 255) / 256, 256, 0, stream>>>(edst, cnt, E);
    {
        const int nb = (N + 1023) / 1024;
        scan_block<<<nb, 1024, 0, stream>>>(cnt, offs, bsum, N);
        scan_bsum<<<1, 64, 0, stream>>>(bsum, nb);
        add_bsum<<<(N + 255) / 256, 256, 0, stream>>>(offs, bsum, N);
    }
    build_perm_gather<<<(E + 255) / 256, 256, 0, stream>>>(
        esrc, edst, ea, offs, src_s, dst_s, ea16, E);

    const short* hin = x16;
    short* houts16[3] = {h16A, h16B, nullptr};

    const int nTilesE = E / 16;                       // 50000
    const int nEB = (nTilesE + 31) / 32;              // 4 waves x 8 tiles per block
    const int nTilesN = (N + 15) / 16;                // 3125
    const int nNB = (nTilesN + 7) / 8;                // 4 waves x 2 tiles per block

    for (int lyr = 0; lyr < 3; ++lyr) {
        float* agg = agg3 + (size_t)lyr * N * H;
        edge_msg_mfma<<<nEB, 256, 0, stream>>>(
            hin, src_s, dst_s, ea16,
            mW1f + (size_t)lyr * 10240, mb1 + (size_t)lyr * H,
            mW2f + (size_t)lyr * 4096,  mb2 + (size_t)lyr * H,
            agg, nTilesE);
        node_update_mfma<<<nNB, 256, 0, stream>>>(
            hin, agg,
            uW1f + (size_t)lyr * 8192, ub1 + (size_t)lyr * H,
            uW2f + (size_t)lyr * 4096, ub2 + (size_t)lyr * H,
            houts16[lyr],
            (lyr == 2) ? batch : (const int*)nullptr,
            pooled, counts, N, nTilesN);
        hin = houts16[lyr];
    }

    head_kernel<<<G, H, 0, stream>>>(pooled, counts, lin1w, lin1b, lin2w, lin2b,
                                     (float*)d_out, G);
}